// Round 3
// baseline (1119.261 us; speedup 1.0000x reference)
//
#include <hip/hip_runtime.h>
#include <hip/hip_bf16.h>

// Problem dims
#define NB 8
#define NC 64
#define NH 256
#define NW 256
#define OHW 131
#define NPIX (131*131)      // 17161
#define HWX (256*256)       // 65536

// db4 filters (dec_lo / dec_hi); cross-correlation taps are DLO[7-j] etc.
static constexpr float DLO[8] = {
    -0.010597401784997278f,  0.032883011666982945f,  0.030841381835986965f,
    -0.18703481171888114f,  -0.02798376941698385f,   0.6308807679295904f,
     0.7148465705525415f,    0.23037781330885523f};
static constexpr float DHI[8] = {
    -0.23037781330885523f,   0.7148465705525415f,   -0.6308807679295904f,
    -0.02798376941698385f,   0.18703481171888114f,   0.030841381835986965f,
    -0.032883011666982945f, -0.010597401784997278f};

__device__ __forceinline__ float b2f(__hip_bfloat16 v) { return __bfloat162float(v); }

__device__ __forceinline__ int refl(int t) {          // symmetric padding reflect
    if (t < 0) return -1 - t;
    if (t >= 256) return 511 - t;
    return t;
}

// ---------------- K0: density[b][c] = mean(x != 0) ----------------
__global__ __launch_bounds__(256) void k_density(const float* __restrict__ x,
                                                 float* __restrict__ density) {
    int bc = blockIdx.x;
    const float* p = x + (size_t)bc * HWX;
    int cnt = 0;
    for (int i = threadIdx.x; i < HWX; i += 256)
        cnt += (p[i] != 0.0f);
    __shared__ int sm[256];
    sm[threadIdx.x] = cnt;
    __syncthreads();
    for (int s = 128; s > 0; s >>= 1) {
        if (threadIdx.x < s) sm[threadIdx.x] += sm[threadIdx.x + s];
        __syncthreads();
    }
    if (threadIdx.x == 0) density[bc] = (float)sm[0] * (1.0f / HWX);
}

// ---------------- K1: separable db4 DWT -> ff (B, 4C, 131, 131) bf16 ----------------
__global__ __launch_bounds__(256) void k_dwt(const float* __restrict__ x,
                                             __hip_bfloat16* __restrict__ ff) {
    int tile = blockIdx.x;                 // 9x9 tiles of 16x16 outputs
    int tr = tile / 9, tc = tile % 9;
    int bc = blockIdx.y;
    int b = bc >> 6, c = bc & 63;
    int oh0 = tr * 16, ow0 = tc * 16;

    __shared__ float t[38][40];
    const float* xp = x + (size_t)bc * HWX;
    for (int idx = threadIdx.x; idx < 38 * 38; idx += 256) {
        int r = idx / 38, cc = idx % 38;
        int gy = refl(2 * oh0 - 6 + r);
        int gx = refl(2 * ow0 - 6 + cc);
        t[r][cc] = xp[gy * NW + gx];
    }
    __syncthreads();

    int ty = threadIdx.x >> 4, tx = threadIdx.x & 15;
    int oh = oh0 + ty, ow = ow0 + tx;
    if (oh < OHW && ow < OHW) {
        float rl[8], rh[8];
#pragma unroll
        for (int i = 0; i < 8; i++) {
            float sl = 0.f, sh = 0.f;
#pragma unroll
            for (int j = 0; j < 8; j++) {
                float v = t[2 * ty + i][2 * tx + j];
                sl += DLO[7 - j] * v;     // g_lo[j] = dec_lo[7-j]
                sh += DHI[7 - j] * v;
            }
            rl[i] = sl; rh[i] = sh;
        }
        float s0 = 0.f, s1 = 0.f, s2 = 0.f, s3 = 0.f;
#pragma unroll
        for (int i = 0; i < 8; i++) {
            s0 += DLO[7 - i] * rl[i];     // H lo, W lo  (aa)
            s1 += DHI[7 - i] * rl[i];     // H hi, W lo  (da)
            s2 += DLO[7 - i] * rh[i];     // H lo, W hi  (ad)
            s3 += DHI[7 - i] * rh[i];     // H hi, W hi  (dd)
        }
        size_t pix = (size_t)oh * OHW + ow;
        size_t base = ((size_t)b * 256 + c) * NPIX + pix;
        ff[base + (size_t)0 * 64 * NPIX] = __float2bfloat16(s0);
        ff[base + (size_t)1 * 64 * NPIX] = __float2bfloat16(s1);
        ff[base + (size_t)2 * 64 * NPIX] = __float2bfloat16(s2);
        ff[base + (size_t)3 * 64 * NPIX] = __float2bfloat16(s3);
    }
}

// ---------------- K2: conv1x1 #1 (K=256 -> M=128) + GN partial sums ----------------
__global__ __launch_bounds__(256) void k_conv1(const __hip_bfloat16* __restrict__ ff,
                                               const float* __restrict__ w1,
                                               const float* __restrict__ b1,
                                               __hip_bfloat16* __restrict__ z,
                                               float* __restrict__ gnsum,
                                               float* __restrict__ gnsq) {
    int p0 = blockIdx.x * 64;
    int b = blockIdx.y;
    __shared__ float wl[8][128];
    __shared__ float fl[8][64];
    float acc[4][8];
#pragma unroll
    for (int i = 0; i < 4; i++)
#pragma unroll
        for (int j = 0; j < 8; j++) acc[i][j] = 0.f;

    int ob = (threadIdx.x & 31) * 4;   // 4 consecutive outputs
    int pb = (threadIdx.x >> 5) * 8;   // 8 consecutive pixels

    for (int k0 = 0; k0 < 256; k0 += 8) {
        __syncthreads();
        if (threadIdx.x < 128) {
            int o = threadIdx.x;
            const float* wp = w1 + o * 256 + k0;
#pragma unroll
            for (int kk = 0; kk < 8; kk++) wl[kk][o] = wp[kk];
        } else {
            int tt = threadIdx.x - 128;
            int kk = tt >> 4;
            int pi = (tt & 15) * 4;
            const __hip_bfloat16* fp = ff + ((size_t)b * 256 + k0 + kk) * NPIX + p0 + pi;
#pragma unroll
            for (int u = 0; u < 4; u++) {
                int p = p0 + pi + u;
                fl[kk][pi + u] = (p < NPIX) ? b2f(fp[u]) : 0.f;
            }
        }
        __syncthreads();
#pragma unroll
        for (int kk = 0; kk < 8; kk++) {
            float wv[4], fv[8];
#pragma unroll
            for (int i = 0; i < 4; i++) wv[i] = wl[kk][ob + i];
#pragma unroll
            for (int j = 0; j < 8; j++) fv[j] = fl[kk][pb + j];
#pragma unroll
            for (int i = 0; i < 4; i++)
#pragma unroll
                for (int j = 0; j < 8; j++) acc[i][j] += wv[i] * fv[j];
        }
    }

    // epilogue: z = acc + b1 (stored bf16), accumulate GN stats from fp32 acc
    float lsum = 0.f, lsq = 0.f;
#pragma unroll
    for (int i = 0; i < 4; i++) {
        int o = ob + i;
        float bias = b1[o];
        __hip_bfloat16* zp = z + ((size_t)b * 128 + o) * NPIX;
#pragma unroll
        for (int j = 0; j < 8; j++) {
            int p = p0 + pb + j;
            if (p < NPIX) {
                float v = acc[i][j] + bias;
                zp[p] = __float2bfloat16(v);
                lsum += v; lsq += v * v;
            }
        }
    }
    __shared__ float gsum[8], gsq[8];
    if (threadIdx.x < 8) { gsum[threadIdx.x] = 0.f; gsq[threadIdx.x] = 0.f; }
    __syncthreads();
    int g = (threadIdx.x & 31) >> 2;   // = o/16
    atomicAdd(&gsum[g], lsum);
    atomicAdd(&gsq[g], lsq);
    __syncthreads();
    if (threadIdx.x < 8) {
        atomicAdd(&gnsum[b * 8 + threadIdx.x], gsum[threadIdx.x]);
        atomicAdd(&gnsq[b * 8 + threadIdx.x], gsq[threadIdx.x]);
    }
}

// ---------------- K3: GN scale/shift + density->gates MLP ----------------
__global__ __launch_bounds__(256) void k_finalize(const float* __restrict__ gnsum,
                                                  const float* __restrict__ gnsq,
                                                  const float* __restrict__ gamma,
                                                  const float* __restrict__ beta,
                                                  const float* __restrict__ density,
                                                  const float* __restrict__ g1,
                                                  const float* __restrict__ gb1,
                                                  const float* __restrict__ g2,
                                                  const float* __restrict__ gb2,
                                                  float* __restrict__ A,
                                                  float* __restrict__ Bs,
                                                  float* __restrict__ gates) {
    __shared__ float mu[64], inv[64];
    int t = threadIdx.x;
    if (t < 64) {
        float n = 16.0f * NPIX;
        float m = gnsum[t] / n;
        float v = gnsq[t] / n - m * m;
        mu[t] = m;
        inv[t] = rsqrtf(v + 1e-5f);
    }
    __syncthreads();
    for (int i = t; i < 1024; i += 256) {
        int b = i >> 7, o = i & 127;
        int g = o >> 4;
        float a = gamma[o] * inv[b * 8 + g];
        A[i] = a;
        Bs[i] = beta[o] - mu[b * 8 + g] * a;
    }
    if (t < 8) {
        int b = t;
        float h[16];
        for (int j = 0; j < 16; j++) {
            float s = gb1[j];
            for (int c = 0; c < 64; c++) s += density[b * 64 + c] * g1[j * 64 + c];
            h[j] = fmaxf(s, 0.f);
        }
        for (int s4 = 0; s4 < 4; s4++) {
            float s = gb2[s4];
            for (int j = 0; j < 16; j++) s += h[j] * g2[s4 * 16 + j];
            gates[b * 4 + s4] = 1.f / (1.f + expf(-s));
        }
    }
}

// ---------------- K4: GN-apply + GELU + conv1x1 #2 (K=128 -> M=256) + gate ----------------
__global__ __launch_bounds__(256) void k_conv2(const __hip_bfloat16* __restrict__ z,
                                               const float* __restrict__ w2,
                                               const float* __restrict__ b2,
                                               const float* __restrict__ A,
                                               const float* __restrict__ Bs,
                                               const float* __restrict__ gates,
                                               __hip_bfloat16* __restrict__ gated) {
    int p0 = blockIdx.x * 32;
    int b = blockIdx.y;
    __shared__ float wl[8][256];
    __shared__ float gl[8][32];
    float acc[4][8];
#pragma unroll
    for (int i = 0; i < 4; i++)
#pragma unroll
        for (int j = 0; j < 8; j++) acc[i][j] = 0.f;

    int mb = (threadIdx.x & 63) * 4;
    int pb = (threadIdx.x >> 6) * 8;
    const float inv_s2 = 0.70710678118654752f;

    for (int k0 = 0; k0 < 128; k0 += 8) {
        __syncthreads();
        {
            int m = threadIdx.x;
            const float* wp = w2 + m * 128 + k0;
#pragma unroll
            for (int kk = 0; kk < 8; kk++) wl[kk][m] = wp[kk];
        }
        {
            int kk = threadIdx.x >> 5, pi = threadIdx.x & 31;
            int p = p0 + pi, k = k0 + kk;
            float v = 0.f;
            if (p < NPIX) {
                float zz = b2f(z[((size_t)b * 128 + k) * NPIX + p]);
                float t2 = A[b * 128 + k] * zz + Bs[b * 128 + k];
                v = 0.5f * t2 * (1.f + erff(t2 * inv_s2));   // exact gelu
            }
            gl[kk][pi] = v;
        }
        __syncthreads();
#pragma unroll
        for (int kk = 0; kk < 8; kk++) {
            float wv[4], fv[8];
#pragma unroll
            for (int i = 0; i < 4; i++) wv[i] = wl[kk][mb + i];
#pragma unroll
            for (int j = 0; j < 8; j++) fv[j] = gl[kk][pb + j];
#pragma unroll
            for (int i = 0; i < 4; i++)
#pragma unroll
                for (int j = 0; j < 8; j++) acc[i][j] += wv[i] * fv[j];
        }
    }

#pragma unroll
    for (int i = 0; i < 4; i++) {
        int m = mb + i;
        int s = m >> 6, c = m & 63;
        float gt = gates[b * 4 + s];
        float bias = b2[m];
        __hip_bfloat16* gp = gated + (((size_t)b * 64 + c) * 4 + s) * NPIX;
#pragma unroll
        for (int j = 0; j < 8; j++) {
            int p = p0 + pb + j;
            if (p < NPIX) gp[p] = __float2bfloat16(gt * (acc[i][j] + bias));
        }
    }
}

// ---------------- K5: iDWT (gated (B,C,4,131,131) -> recon fp32 in d_out) ----------------
__global__ __launch_bounds__(256) void k_idwt(const __hip_bfloat16* __restrict__ gated,
                                              float* __restrict__ recon) {
    int tile = blockIdx.x;                 // 16x16 tiles of 16x16 outputs
    int ty0 = (tile >> 4) * 16, tx0 = (tile & 15) * 16;
    int bc = blockIdx.y;

    __shared__ float gl[4][11][12];
    int ohb0 = ty0 >> 1, owb0 = tx0 >> 1;
    const __hip_bfloat16* gp = gated + (size_t)bc * 4 * NPIX;
    for (int idx = threadIdx.x; idx < 4 * 121; idx += 256) {
        int s = idx / 121, rem = idx % 121;
        int r = rem / 11, cc = rem % 11;
        int oh = ohb0 + r, ow = owb0 + cc;
        float v = (oh < OHW && ow < OHW) ? b2f(gp[(size_t)s * NPIX + oh * OHW + ow]) : 0.f;
        gl[s][r][cc] = v;
    }
    __syncthreads();

    int ty = threadIdx.x >> 4, tx = threadIdx.x & 15;
    int y = ty0 + ty, x = tx0 + tx;
    int pey = (y & 1) ^ 1;                 // y even -> taps at odd dy
    int pex = (x & 1) ^ 1;
    float hl[4], hh[4], wlv[4], wh[4];
#pragma unroll
    for (int u = 0; u < 4; u++) {
        hl[u] = DLO[2 * u + pey]; hh[u] = DHI[2 * u + pey];
        wlv[u] = DLO[2 * u + pex]; wh[u] = DHI[2 * u + pex];
    }
    int r0 = ty >> 1, c0 = tx >> 1;
    float s = 0.f;
#pragma unroll
    for (int u = 0; u < 4; u++) {
        float rowlo = 0.f, rowhi = 0.f;
#pragma unroll
        for (int v = 0; v < 4; v++) {
            rowlo += wlv[v] * gl[0][r0 + u][c0 + v] + wh[v] * gl[2][r0 + u][c0 + v];
            rowhi += wlv[v] * gl[1][r0 + u][c0 + v] + wh[v] * gl[3][r0 + u][c0 + v];
        }
        s += hl[u] * rowlo + hh[u] * rowhi;
    }
    recon[(size_t)bc * HWX + y * NW + x] = s;
}

// ---------------- K6: final conv1x1 on concat([x, recon]) -> fp32 out (in place over recon) ----------------
// Safe in-place: each block reads recon only at its own pixel slice [p0,p0+64),
// all reads complete before the K-loop's final barrier, then writes out at the
// same slice. Pixel slices are disjoint across blocks.
__global__ __launch_bounds__(256) void k_final(const float* __restrict__ x,
                                               const float* __restrict__ recon,
                                               const float* __restrict__ wf,
                                               const float* __restrict__ bfv,
                                               float* __restrict__ out) {
    int p0 = blockIdx.x * 64;
    int b = blockIdx.y;
    __shared__ float wl[8][64];
    __shared__ float fl[8][64];
    float acc[4][4];
#pragma unroll
    for (int i = 0; i < 4; i++)
#pragma unroll
        for (int j = 0; j < 4; j++) acc[i][j] = 0.f;

    int ob = (threadIdx.x & 15) * 4;
    int pb = (threadIdx.x >> 4) * 4;

    for (int k0 = 0; k0 < 128; k0 += 8) {
        __syncthreads();
#pragma unroll
        for (int u = 0; u < 2; u++) {
            int idx = threadIdx.x * 2 + u;
            int kk = idx >> 6, pi = idx & 63;
            int k = k0 + kk, p = p0 + pi;
            float v;
            if (k < 64) v = x[((size_t)b * 64 + k) * HWX + p];
            else        v = recon[((size_t)b * 64 + (k - 64)) * HWX + p];
            fl[kk][pi] = v;
        }
        if (threadIdx.x < 64) {
            int o = threadIdx.x;
            const float* wp = wf + o * 128 + k0;
#pragma unroll
            for (int kk = 0; kk < 8; kk++) wl[kk][o] = wp[kk];
        }
        __syncthreads();
#pragma unroll
        for (int kk = 0; kk < 8; kk++) {
            float wv[4], fv[4];
#pragma unroll
            for (int i = 0; i < 4; i++) wv[i] = wl[kk][ob + i];
#pragma unroll
            for (int j = 0; j < 4; j++) fv[j] = fl[kk][pb + j];
#pragma unroll
            for (int i = 0; i < 4; i++)
#pragma unroll
                for (int j = 0; j < 4; j++) acc[i][j] += wv[i] * fv[j];
        }
    }
#pragma unroll
    for (int i = 0; i < 4; i++) {
        int o = ob + i;
        float bias = bfv[o];
        float* op = out + ((size_t)b * 64 + o) * HWX + p0;
#pragma unroll
        for (int j = 0; j < 4; j++)
            op[pb + j] = acc[i][j] + bias;
    }
}

extern "C" void kernel_launch(void* const* d_in, const int* in_sizes, int n_in,
                              void* d_out, int out_size, void* d_ws, size_t ws_size,
                              hipStream_t stream) {
    // Reference dtypes are float32 for ALL inputs and the output.
    const float* x     = (const float*)d_in[0];
    const float* w1    = (const float*)d_in[1];
    const float* b1    = (const float*)d_in[2];
    const float* gamma = (const float*)d_in[3];
    const float* beta  = (const float*)d_in[4];
    const float* w2    = (const float*)d_in[5];
    const float* b2    = (const float*)d_in[6];
    const float* g1    = (const float*)d_in[7];
    const float* gb1   = (const float*)d_in[8];
    const float* g2    = (const float*)d_in[9];
    const float* gb2   = (const float*)d_in[10];
    const float* wf    = (const float*)d_in[11];
    const float* bfv   = (const float*)d_in[12];

    float* wsf = (float*)d_ws;
    // stats block (floats): [0,512) density, [512,576) gnsum, [576,640) gnsq,
    //                       [640,1664) A, [1664,2688) Bs, [2688,2720) gates
    float* stats = wsf;
    __hip_bfloat16* ffb = (__hip_bfloat16*)(wsf + 4096);      // 35,145,728 bf16 (reused as `gated`)
    __hip_bfloat16* zb  = ffb + (size_t)35145728;             // 17,572,864 bf16
    // total ws usage: 16,384 + 70,291,456 + 35,145,728 = 105,453,568 bytes (~101 MB)
    float* recon = (float*)d_out;                             // recon lives in d_out (fp32)

    hipMemsetAsync(stats + 512, 0, 128 * sizeof(float), stream);

    k_density<<<dim3(512), 256, 0, stream>>>(x, stats);
    k_dwt<<<dim3(81, 512), 256, 0, stream>>>(x, ffb);
    k_conv1<<<dim3(269, 8), 256, 0, stream>>>(ffb, w1, b1, zb, stats + 512, stats + 576);
    k_finalize<<<dim3(1), 256, 0, stream>>>(stats + 512, stats + 576, gamma, beta,
                                            stats, g1, gb1, g2, gb2,
                                            stats + 640, stats + 1664, stats + 2688);
    k_conv2<<<dim3(537, 8), 256, 0, stream>>>(zb, w2, b2, stats + 640, stats + 1664,
                                              stats + 2688, ffb /* gated overwrites ff */);
    k_idwt<<<dim3(256, 512), 256, 0, stream>>>(ffb, recon);
    k_final<<<dim3(1024, 8), 256, 0, stream>>>(x, recon, wf, bfv,
                                               (float*)d_out);
}